// Round 7
// baseline (182.892 us; speedup 1.0000x reference)
//
#include <hip/hip_runtime.h>

// Problem constants: N=20000, T=4, F_IN=F_OUT=64, E=640000
#define N_NODES 20000
#define T_STEPS 4
#define F_DIM   64
#define E_EDGES 640000
#define ROWS    (N_NODES * T_STEPS)   // 80000
#define ROW_ELEMS (T_STEPS * F_DIM)   // 256 elems per node row

#define SCATTER_BLOCKS   (E_EDGES / 256)      // 2500 (1 edge/thread: max TLP)
#define TRANSFORM_BLOCKS (ROWS / 64)          // 1250
#define OVF_CAP          4096

#define NREG   8          // one bucket segment-set per XCD
#define CAPA   8          // hot slots per (node, region): exactly 1 cache line
#define CAPB   8          // cold spill slots (P(seg>8) ~ 2.1%)
#define CAPT   (CAPA + CAPB)

__device__ __forceinline__ unsigned short f32_to_bf16_rne(float f) {
    unsigned u = __float_as_uint(f);
    u += 0x7FFFu + ((u >> 16) & 1u);
    return (unsigned short)(u >> 16);
}
__device__ __forceinline__ float bf16_to_f32(unsigned short h) {
    return __uint_as_float((unsigned)h << 16);
}
// 12-bit fixed-point weight in [0,1): abs err <= 2^-13 (better than bf16).
__device__ __forceinline__ unsigned w_to_u12(float f) {
    unsigned q = __float2uint_rn(f * 4096.0f);
    return q > 4095u ? 4095u : q;
}

// ---------------------------------------------------------------------------
// Fused kernel.
//  R6 post-mortem: WRITE -8.4MB bought only -1us -> build is NOT byte-bound;
//  it is bound by the 2.56M atomic+store latency chains running at ~10
//  waves/CU after the transform blocks (which finish in ~3us) drain. R7:
//  1 edge/thread, 2500 scatter blocks -> scatter phase runs at the 32-wave
//  HW occupancy cap for its whole duration; 4x the independent atomic
//  chains in flight. Byte layout unchanged (hot A line / cold B spill,
//  single-writer-XCD segments via XCC_ID).
//  blocks [0, 2500):      bucket scatter — 8B record: src(16b)|w0..w3(12b).
//  blocks [2500, 3750):   transform — y = x @ W^T (64x64 fp32) stored bf16.
// ---------------------------------------------------------------------------
__global__ __launch_bounds__(256) void fused_build_kernel(
    const float* __restrict__ x, const float* __restrict__ W,
    unsigned short* __restrict__ yb,
    const int* __restrict__ src, const int* __restrict__ dst,
    const float* __restrict__ ew,
    int* __restrict__ cnt, uint2* __restrict__ bktA, uint2* __restrict__ bktB,
    int4* __restrict__ ovf, int* __restrict__ ovf_cnt)
{
    __shared__ float wt[64 * 64];   // W^T, stride 64: 16 KB total

    if (blockIdx.x < SCATTER_BLOCKS) {
        unsigned xcc;
        asm volatile("s_getreg_b32 %0, hwreg(HW_REG_XCC_ID)" : "=s"(xcc));
        const int reg = (int)(xcc & 7u);      // any value 0..7 is correct
        int* creg = cnt + (size_t)reg * N_NODES;

        const int e = blockIdx.x * 256 + threadIdx.x;   // 1 edge per thread
        const unsigned w0 = w_to_u12(ew[e]);
        const unsigned w1 = w_to_u12(ew[E_EDGES + e]);
        const unsigned w2 = w_to_u12(ew[2 * E_EDGES + e]);
        const unsigned w3 = w_to_u12(ew[3 * E_EDGES + e]);
        const unsigned s  = (unsigned)src[e];
        const unsigned lo = s | (w0 << 16) | (w1 << 28);       // w1 bits 0..3
        const unsigned hi = (w1 >> 4) | (w2 << 8) | (w3 << 20);
        const int d = dst[e];
        const int pos = atomicAdd(&creg[d], 1);
        const uint2 rec = make_uint2(lo, hi);
        if (pos < CAPA) {
            bktA[((size_t)d * NREG + reg) * CAPA + pos] = rec;
        } else if (pos < CAPT) {
            bktB[((size_t)d * NREG + reg) * CAPB + (pos - CAPA)] = rec;
        } else {
            const int o = atomicAdd(ovf_cnt, 1);
            if (o < OVF_CAP) { int4 r; r.x = (int)rec.x; r.y = (int)rec.y; r.z = d; r.w = 0; ovf[o] = r; }
        }
        return;
    }

    // ---- transform part: y = x @ W^T, x streamed from global (plain loads) ----
    const int tid  = threadIdx.x;
    const int row0 = (blockIdx.x - SCATTER_BLOCKS) * 64;

    // W^T into LDS: wt[f*64 + o] = W[o*64 + f].
    {
        const int o  = tid & 63;
        const int fb = (tid >> 6) * 16;
#pragma unroll
        for (int k = 0; k < 16; ++k) {
            const int f = fb + k;
            wt[f * 64 + o] = W[o * 64 + f];
        }
    }
    __syncthreads();

    const int rg = tid >> 4;          // 0..15: row group (4 rows)
    const int oq = (tid & 15) * 4;    // output quad

    float acc[4][4];
#pragma unroll
    for (int i = 0; i < 4; ++i)
#pragma unroll
        for (int j = 0; j < 4; ++j) acc[i][j] = 0.0f;

    const float4* xg4 = (const float4*)(x + (size_t)(row0 + rg * 4) * 64);

#pragma unroll 4
    for (int fc = 0; fc < 16; ++fc) {
        float4 xv[4];
#pragma unroll
        for (int i = 0; i < 4; ++i) xv[i] = xg4[i * 16 + fc];
#pragma unroll
        for (int j = 0; j < 4; ++j) {
            const int f = fc * 4 + j;
            const float4 w4 = *(const float4*)&wt[f * 64 + oq];
            const float xj0 = j == 0 ? xv[0].x : j == 1 ? xv[0].y : j == 2 ? xv[0].z : xv[0].w;
            const float xj1 = j == 0 ? xv[1].x : j == 1 ? xv[1].y : j == 2 ? xv[1].z : xv[1].w;
            const float xj2 = j == 0 ? xv[2].x : j == 1 ? xv[2].y : j == 2 ? xv[2].z : xv[2].w;
            const float xj3 = j == 0 ? xv[3].x : j == 1 ? xv[3].y : j == 2 ? xv[3].z : xv[3].w;
            acc[0][0] += xj0 * w4.x; acc[0][1] += xj0 * w4.y; acc[0][2] += xj0 * w4.z; acc[0][3] += xj0 * w4.w;
            acc[1][0] += xj1 * w4.x; acc[1][1] += xj1 * w4.y; acc[1][2] += xj1 * w4.z; acc[1][3] += xj1 * w4.w;
            acc[2][0] += xj2 * w4.x; acc[2][1] += xj2 * w4.y; acc[2][2] += xj2 * w4.z; acc[2][3] += xj2 * w4.w;
            acc[3][0] += xj3 * w4.x; acc[3][1] += xj3 * w4.y; acc[3][2] += xj3 * w4.z; acc[3][3] += xj3 * w4.w;
        }
    }

#pragma unroll
    for (int i = 0; i < 4; ++i) {
        const int r = row0 + rg * 4 + i;
        ushort4 h;
        h.x = f32_to_bf16_rne(acc[i][0]);
        h.y = f32_to_bf16_rne(acc[i][1]);
        h.z = f32_to_bf16_rne(acc[i][2]);
        h.w = f32_to_bf16_rne(acc[i][3]);
        *(ushort4*)(yb + (size_t)r * 64 + oq) = h;
    }
}

// Per-lane weight decode: t = lane>>4 selects w_t, shift = 16 + 12*t.
__device__ __forceinline__ float dec_w(uint2 r, int t) {
    const unsigned long long pk = (unsigned long long)r.x |
                                  ((unsigned long long)r.y << 32);
    const unsigned q = (unsigned)(pk >> (16 + 12 * t)) & 0xFFFu;
    return (float)q * (1.0f / 4096.0f);
}

// 4-record batch: all register indices compile-time (rule #20).
#define BATCH4(RP, K0)                                                        \
    {                                                                         \
        const uint2 R0 = (RP)[(K0) + 0], R1 = (RP)[(K0) + 1],                 \
                    R2 = (RP)[(K0) + 2], R3 = (RP)[(K0) + 3];                 \
        const ushort4 V0 = *(const ushort4*)(yb + (size_t)(R0.x & 0xFFFFu) * ROW_ELEMS + l4); \
        const ushort4 V1 = *(const ushort4*)(yb + (size_t)(R1.x & 0xFFFFu) * ROW_ELEMS + l4); \
        const ushort4 V2 = *(const ushort4*)(yb + (size_t)(R2.x & 0xFFFFu) * ROW_ELEMS + l4); \
        const ushort4 V3 = *(const ushort4*)(yb + (size_t)(R3.x & 0xFFFFu) * ROW_ELEMS + l4); \
        float w;                                                              \
        w = dec_w(R0, t);                                                     \
        acc.x += bf16_to_f32(V0.x) * w; acc.y += bf16_to_f32(V0.y) * w;       \
        acc.z += bf16_to_f32(V0.z) * w; acc.w += bf16_to_f32(V0.w) * w;       \
        w = dec_w(R1, t);                                                     \
        acc.x += bf16_to_f32(V1.x) * w; acc.y += bf16_to_f32(V1.y) * w;       \
        acc.z += bf16_to_f32(V1.z) * w; acc.w += bf16_to_f32(V1.w) * w;       \
        w = dec_w(R2, t);                                                     \
        acc.x += bf16_to_f32(V2.x) * w; acc.y += bf16_to_f32(V2.y) * w;       \
        acc.z += bf16_to_f32(V2.z) * w; acc.w += bf16_to_f32(V2.w) * w;       \
        w = dec_w(R3, t);                                                     \
        acc.x += bf16_to_f32(V3.x) * w; acc.y += bf16_to_f32(V3.y) * w;       \
        acc.z += bf16_to_f32(V3.z) * w; acc.w += bf16_to_f32(V3.w) * w;       \
    }

// ---------------------------------------------------------------------------
// Accumulate: one 64-lane wave per node, 4 nodes/block. Lane l owns elems
// [l*4, l*4+4); t = l>>4. Hot path reads the dense A row (8 lines/node,
// contiguous); B spill read only when a segment exceeded 8 (P~2.1%).
// Overflow fixup fused (normally empty). Unchanged from R6 (52.0us).
// ---------------------------------------------------------------------------
__global__ __launch_bounds__(256) void accumulate_kernel(
    const unsigned short* __restrict__ yb, const int* __restrict__ cnt,
    const uint2* __restrict__ bktA, const uint2* __restrict__ bktB,
    const int4* __restrict__ ovf, const int* __restrict__ ovf_cnt,
    const float* __restrict__ b, float* __restrict__ out)
{
    const int lane = threadIdx.x & 63;
    const int n    = blockIdx.x * 4 + (threadIdx.x >> 6);
    const int t    = lane >> 4;
    const int l4   = lane * 4;

    // 8 per-region degrees (independent broadcast loads, issue together)
    int degc[NREG];
#pragma unroll
    for (int r = 0; r < NREG; ++r) {
        int d = cnt[(size_t)r * N_NODES + n];
        degc[r] = d > CAPT ? CAPT : d;
    }

    float4 acc = make_float4(0.f, 0.f, 0.f, 0.f);

#pragma unroll
    for (int r = 0; r < NREG; ++r) {
        const uint2* pa = bktA + ((size_t)n * NREG + r) * CAPA;
        const int d = degc[r];
        int k = 0;
        if (d >= 4) {
            BATCH4(pa, 0); k = 4;
            if (d >= 8) {
                BATCH4(pa, 4); k = 8;
                if (d > 8) {   // rare spill (P ~ 2.1%)
                    const uint2* pb = bktB + ((size_t)n * NREG + r) * CAPB;
                    if (d >= 12) {
                        BATCH4(pb, 0); k = 12;
                        if (d >= 16) { BATCH4(pb, 4); k = 16; }
                    }
                    for (; k < d; ++k) {
                        const uint2 rr = pb[k - 8];
                        const float w = dec_w(rr, t);
                        const ushort4 v = *(const ushort4*)(yb + (size_t)(rr.x & 0xFFFFu) * ROW_ELEMS + l4);
                        acc.x += bf16_to_f32(v.x) * w;
                        acc.y += bf16_to_f32(v.y) * w;
                        acc.z += bf16_to_f32(v.z) * w;
                        acc.w += bf16_to_f32(v.w) * w;
                    }
                }
            }
        }
        for (; k < d && k < 8; ++k) {      // hot tail (deg < 8 remainder)
            const uint2 rr = pa[k];
            const float w = dec_w(rr, t);
            const ushort4 v = *(const ushort4*)(yb + (size_t)(rr.x & 0xFFFFu) * ROW_ELEMS + l4);
            acc.x += bf16_to_f32(v.x) * w;
            acc.y += bf16_to_f32(v.y) * w;
            acc.z += bf16_to_f32(v.z) * w;
            acc.w += bf16_to_f32(v.w) * w;
        }
    }

    // ---- fused overflow fixup (normally m == 0: one broadcast load) ----
    {
        int m = *ovf_cnt;
        if (m > OVF_CAP) m = OVF_CAP;
        for (int i = 0; i < m; ++i) {
            const int4 rr = ovf[i];
            if (rr.z == n) {
                const uint2 r2 = make_uint2((unsigned)rr.x, (unsigned)rr.y);
                const float w = dec_w(r2, t);
                const ushort4 v = *(const ushort4*)(yb + (size_t)(r2.x & 0xFFFFu) * ROW_ELEMS + l4);
                acc.x += bf16_to_f32(v.x) * w;
                acc.y += bf16_to_f32(v.y) * w;
                acc.z += bf16_to_f32(v.z) * w;
                acc.w += bf16_to_f32(v.w) * w;
            }
        }
    }

    const float4 bv = *(const float4*)(b + (lane & 15) * 4);
    acc.x += bv.x; acc.y += bv.y; acc.z += bv.z; acc.w += bv.w;
    *(float4*)(out + (size_t)n * ROW_ELEMS + l4) = acc;
}

extern "C" void kernel_launch(void* const* d_in, const int* in_sizes, int n_in,
                              void* d_out, int out_size, void* d_ws, size_t ws_size,
                              hipStream_t stream) {
    const float* x   = (const float*)d_in[0];  // (N,T,64)
    const float* ew  = (const float*)d_in[1];  // (T,E)
    const int*   src = (const int*)  d_in[2];  // (E,)
    const int*   dst = (const int*)  d_in[3];  // (E,)
    const float* W   = (const float*)d_in[4];  // (64,64)
    const float* b   = (const float*)d_in[5];  // (64,)
    float*       out = (float*)d_out;          // (N,T,64)

    char* ws = (char*)d_ws;
    size_t off = 0;
    auto alloc = [&](size_t bytes) {
        void* p = ws + off;
        off += (bytes + 255) & ~(size_t)255;
        return p;
    };
    unsigned short* yb  = (unsigned short*)alloc((size_t)ROWS * 64 * 2);             // 10.24 MB
    int*            cnt = (int*) alloc(((size_t)NREG * N_NODES + 1) * sizeof(int));  // 640 KB
    int4*           ovf = (int4*)alloc((size_t)OVF_CAP * sizeof(int4));              // 64 KB
    uint2*          bktA = (uint2*)alloc((size_t)N_NODES * NREG * CAPA * sizeof(uint2)); // 10.24 MB hot
    uint2*          bktB = (uint2*)alloc((size_t)N_NODES * NREG * CAPB * sizeof(uint2)); // 10.24 MB cold
    int*            ovf_cnt = cnt + (size_t)NREG * N_NODES;
    (void)ws_size;

    hipError_t err = hipMemsetAsync(cnt, 0, ((size_t)NREG * N_NODES + 1) * sizeof(int), stream);
    (void)err;
    fused_build_kernel<<<SCATTER_BLOCKS + TRANSFORM_BLOCKS, 256, 0, stream>>>(
        x, W, yb, src, dst, ew, cnt, bktA, bktB, ovf, ovf_cnt);
    accumulate_kernel<<<N_NODES / 4, 256, 0, stream>>>(
        yb, cnt, bktA, bktB, ovf, ovf_cnt, b, out);
}

// Round 8
// 176.099 us; speedup vs baseline: 1.0386x; 1.0386x over previous
//
#include <hip/hip_runtime.h>

// Problem constants: N=20000, T=4, F_IN=F_OUT=64, E=640000
#define N_NODES 20000
#define T_STEPS 4
#define F_DIM   64
#define E_EDGES 640000
#define ROWS    (N_NODES * T_STEPS)   // 80000
#define ROW_ELEMS (T_STEPS * F_DIM)   // 256 elems per node row

#define CH     128                    // edge chunks (1 block each in hist/scatter)
#define CHE    (E_EDGES / CH)         // 5000 edges per chunk
#define NB2    ((N_NODES + 255) / 256) // 79 scan blocks
#define TRANSFORM_BLOCKS (ROWS / 64)  // 1250

__device__ __forceinline__ unsigned short f32_to_bf16_rne(float f) {
    unsigned u = __float_as_uint(f);
    u += 0x7FFFu + ((u >> 16) & 1u);
    return (unsigned short)(u >> 16);
}
__device__ __forceinline__ float bf16_to_f32(unsigned short h) {
    return __uint_as_float((unsigned)h << 16);
}
// 12-bit fixed-point weight in [0,1): abs err <= 2^-13 (better than bf16).
__device__ __forceinline__ unsigned w_to_u12(float f) {
    unsigned q = __float2uint_rn(f * 4096.0f);
    return q > 4095u ? 4095u : q;
}

// ---------------------------------------------------------------------------
// R7 post-mortem ledger: payload size x, byte count x (-8MB -> -1us),
// occupancy x (32->57%, no delta), TLP x (4x blocks -> WORSE). The only
// invariant is the 640k device-scope atomicAdds, which execute at the
// fabric/MALL coherence point (per-XCD L2s non-coherent). R8 removes global
// atomics entirely: deterministic CSR via LDS-only ranks.
//   K1 hist:    128 blocks; LDS histogram (2x16-bit counts packed/int,
//               40KB); writes cntmat[128][20000] coalesced.
//   K2a scan:   per-node prefix over chunks -> base[c][n]; block-level
//               exclusive scan of degrees -> local[n], blocksum.
//   K2b scan:   79-entry serial scan -> blockoff.
//   K3 scatter: recompute rank via LDS atomicAdd (any order = valid rank),
//               slot = blockoff[n>>8]+local[n]+base[c][n]+rank; ONE plain
//               8B store per edge. Transform (y = x@W^T, bf16) fused into
//               the same dispatch. No memset, no overflow path (CSR exact).
// ---------------------------------------------------------------------------

__global__ __launch_bounds__(256) void hist_kernel(
    const int* __restrict__ dst, unsigned short* __restrict__ cntmat)
{
    __shared__ int h[N_NODES / 2];   // 2 nodes per int (16-bit halves), 40KB
    const int tid = threadIdx.x;
    for (int i = tid; i < N_NODES / 2; i += 256) h[i] = 0;
    __syncthreads();
    const int c = blockIdx.x;
#pragma unroll 4
    for (int j = 0; j < 20; ++j) {
        const int idx = j * 256 + tid;
        if (idx < CHE) {
            const int n = dst[c * CHE + idx];
            atomicAdd(&h[n >> 1], 1 << (16 * (n & 1)));
        }
    }
    __syncthreads();
    unsigned* crow = (unsigned*)(cntmat + (size_t)c * N_NODES);
    for (int i = tid; i < N_NODES / 2; i += 256) crow[i] = (unsigned)h[i];
}

__global__ __launch_bounds__(256) void scan_a_kernel(
    const unsigned short* __restrict__ cntmat, unsigned short* __restrict__ base,
    int* __restrict__ local, unsigned short* __restrict__ deg,
    int* __restrict__ blocksum)
{
    __shared__ int s[256];
    const int tid = threadIdx.x;
    const int n = blockIdx.x * 256 + tid;
    int run = 0;
    if (n < N_NODES) {
        for (int c = 0; c < CH; ++c) {
            const unsigned short u = cntmat[(size_t)c * N_NODES + n];
            base[(size_t)c * N_NODES + n] = (unsigned short)run;
            run += u;
        }
        deg[n] = (unsigned short)run;
    }
    s[tid] = run;
    __syncthreads();
    // Hillis-Steele inclusive scan over 256 threads
    for (int o = 1; o < 256; o <<= 1) {
        const int v = (tid >= o) ? s[tid - o] : 0;
        __syncthreads();
        s[tid] += v;
        __syncthreads();
    }
    if (n < N_NODES) local[n] = s[tid] - run;   // exclusive prefix in block
    if (tid == 255) blocksum[blockIdx.x] = s[255];
}

__global__ void scan_b_kernel(const int* __restrict__ blocksum,
                              int* __restrict__ blockoff)
{
    if (threadIdx.x == 0) {
        int run = 0;
        for (int i = 0; i < NB2; ++i) { blockoff[i] = run; run += blocksum[i]; }
    }
}

__global__ __launch_bounds__(256) void scatter_transform_kernel(
    const float* __restrict__ x, const float* __restrict__ W,
    unsigned short* __restrict__ yb,
    const int* __restrict__ src, const int* __restrict__ dst,
    const float* __restrict__ ew,
    const unsigned short* __restrict__ base, const int* __restrict__ local,
    const int* __restrict__ blockoff, uint2* __restrict__ rec)
{
    __shared__ int smem[N_NODES / 2];   // 40KB; transform reuses first 16KB

    if (blockIdx.x < CH) {
        const int tid = threadIdx.x;
        for (int i = tid; i < N_NODES / 2; i += 256) smem[i] = 0;
        __syncthreads();
        const int c = blockIdx.x;
        const unsigned short* brow = base + (size_t)c * N_NODES;
#pragma unroll 4
        for (int j = 0; j < 20; ++j) {
            const int idx = j * 256 + tid;
            if (idx < CHE) {
                const int e = c * CHE + idx;
                const unsigned w0 = w_to_u12(ew[e]);
                const unsigned w1 = w_to_u12(ew[E_EDGES + e]);
                const unsigned w2 = w_to_u12(ew[2 * E_EDGES + e]);
                const unsigned w3 = w_to_u12(ew[3 * E_EDGES + e]);
                const unsigned s  = (unsigned)src[e];
                const unsigned lo = s | (w0 << 16) | (w1 << 28);
                const unsigned hi = (w1 >> 4) | (w2 << 8) | (w3 << 20);
                const int n = dst[e];
                const int sh = 16 * (n & 1);
                const int old = atomicAdd(&smem[n >> 1], 1 << sh);
                const int rank = (old >> sh) & 0xFFFF;
                const int slot = blockoff[n >> 8] + local[n] + (int)brow[n] + rank;
                rec[slot] = make_uint2(lo, hi);
            }
        }
        return;
    }

    // ---- transform: y = x @ W^T (64x64 fp32) stored bf16 ----
    float* wt = (float*)smem;           // 16KB of the 40KB block
    const int tid  = threadIdx.x;
    const int row0 = (blockIdx.x - CH) * 64;

    {
        const int o  = tid & 63;
        const int fb = (tid >> 6) * 16;
#pragma unroll
        for (int k = 0; k < 16; ++k) {
            const int f = fb + k;
            wt[f * 64 + o] = W[o * 64 + f];
        }
    }
    __syncthreads();

    const int rg = tid >> 4;          // 0..15: row group (4 rows)
    const int oq = (tid & 15) * 4;    // output quad

    float acc[4][4];
#pragma unroll
    for (int i = 0; i < 4; ++i)
#pragma unroll
        for (int j = 0; j < 4; ++j) acc[i][j] = 0.0f;

    const float4* xg4 = (const float4*)(x + (size_t)(row0 + rg * 4) * 64);

#pragma unroll 4
    for (int fc = 0; fc < 16; ++fc) {
        float4 xv[4];
#pragma unroll
        for (int i = 0; i < 4; ++i) xv[i] = xg4[i * 16 + fc];
#pragma unroll
        for (int j = 0; j < 4; ++j) {
            const int f = fc * 4 + j;
            const float4 w4 = *(const float4*)&wt[f * 64 + oq];
            const float xj0 = j == 0 ? xv[0].x : j == 1 ? xv[0].y : j == 2 ? xv[0].z : xv[0].w;
            const float xj1 = j == 0 ? xv[1].x : j == 1 ? xv[1].y : j == 2 ? xv[1].z : xv[1].w;
            const float xj2 = j == 0 ? xv[2].x : j == 1 ? xv[2].y : j == 2 ? xv[2].z : xv[2].w;
            const float xj3 = j == 0 ? xv[3].x : j == 1 ? xv[3].y : j == 2 ? xv[3].z : xv[3].w;
            acc[0][0] += xj0 * w4.x; acc[0][1] += xj0 * w4.y; acc[0][2] += xj0 * w4.z; acc[0][3] += xj0 * w4.w;
            acc[1][0] += xj1 * w4.x; acc[1][1] += xj1 * w4.y; acc[1][2] += xj1 * w4.z; acc[1][3] += xj1 * w4.w;
            acc[2][0] += xj2 * w4.x; acc[2][1] += xj2 * w4.y; acc[2][2] += xj2 * w4.z; acc[2][3] += xj2 * w4.w;
            acc[3][0] += xj3 * w4.x; acc[3][1] += xj3 * w4.y; acc[3][2] += xj3 * w4.z; acc[3][3] += xj3 * w4.w;
        }
    }

#pragma unroll
    for (int i = 0; i < 4; ++i) {
        const int r = row0 + rg * 4 + i;
        ushort4 h;
        h.x = f32_to_bf16_rne(acc[i][0]);
        h.y = f32_to_bf16_rne(acc[i][1]);
        h.z = f32_to_bf16_rne(acc[i][2]);
        h.w = f32_to_bf16_rne(acc[i][3]);
        *(ushort4*)(yb + (size_t)r * 64 + oq) = h;
    }
}

// Per-lane weight decode: t = lane>>4 selects w_t, shift = 16 + 12*t.
__device__ __forceinline__ float dec_w(uint2 r, int t) {
    const unsigned long long pk = (unsigned long long)r.x |
                                  ((unsigned long long)r.y << 32);
    const unsigned q = (unsigned)(pk >> (16 + 12 * t)) & 0xFFFu;
    return (float)q * (1.0f / 4096.0f);
}

// 4-record batch: all register indices compile-time (rule #20).
#define BATCH4(RP, K0)                                                        \
    {                                                                         \
        const uint2 R0 = (RP)[(K0) + 0], R1 = (RP)[(K0) + 1],                 \
                    R2 = (RP)[(K0) + 2], R3 = (RP)[(K0) + 3];                 \
        const ushort4 V0 = *(const ushort4*)(yb + (size_t)(R0.x & 0xFFFFu) * ROW_ELEMS + l4); \
        const ushort4 V1 = *(const ushort4*)(yb + (size_t)(R1.x & 0xFFFFu) * ROW_ELEMS + l4); \
        const ushort4 V2 = *(const ushort4*)(yb + (size_t)(R2.x & 0xFFFFu) * ROW_ELEMS + l4); \
        const ushort4 V3 = *(const ushort4*)(yb + (size_t)(R3.x & 0xFFFFu) * ROW_ELEMS + l4); \
        float w;                                                              \
        w = dec_w(R0, t);                                                     \
        acc.x += bf16_to_f32(V0.x) * w; acc.y += bf16_to_f32(V0.y) * w;       \
        acc.z += bf16_to_f32(V0.z) * w; acc.w += bf16_to_f32(V0.w) * w;       \
        w = dec_w(R1, t);                                                     \
        acc.x += bf16_to_f32(V1.x) * w; acc.y += bf16_to_f32(V1.y) * w;       \
        acc.z += bf16_to_f32(V1.z) * w; acc.w += bf16_to_f32(V1.w) * w;       \
        w = dec_w(R2, t);                                                     \
        acc.x += bf16_to_f32(V2.x) * w; acc.y += bf16_to_f32(V2.y) * w;       \
        acc.z += bf16_to_f32(V2.z) * w; acc.w += bf16_to_f32(V2.w) * w;       \
        w = dec_w(R3, t);                                                     \
        acc.x += bf16_to_f32(V3.x) * w; acc.y += bf16_to_f32(V3.y) * w;       \
        acc.z += bf16_to_f32(V3.z) * w; acc.w += bf16_to_f32(V3.w) * w;       \
    }

// ---------------------------------------------------------------------------
// Accumulate: one 64-lane wave per node, 4 nodes/block. Lane l owns elems
// [l*4, l*4+4); t = l>>4. CSR rows: contiguous ~32 records (~4 lines/node,
// exact degree — no cap, no overflow fixup).
// ---------------------------------------------------------------------------
__global__ __launch_bounds__(256) void accumulate_kernel(
    const unsigned short* __restrict__ yb, const uint2* __restrict__ rec,
    const int* __restrict__ local, const unsigned short* __restrict__ deg,
    const int* __restrict__ blockoff,
    const float* __restrict__ b, float* __restrict__ out)
{
    const int lane = threadIdx.x & 63;
    const int n    = blockIdx.x * 4 + (threadIdx.x >> 6);
    const int t    = lane >> 4;
    const int l4   = lane * 4;

    const int start = blockoff[n >> 8] + local[n];
    const int d     = (int)deg[n];
    const uint2* rp = rec + start;

    float4 acc = make_float4(0.f, 0.f, 0.f, 0.f);

    int k = 0;
    for (; k + 8 <= d; k += 8) { BATCH4(rp, k); BATCH4(rp, k + 4); }
    if (k + 4 <= d) { BATCH4(rp, k); k += 4; }
    for (; k < d; ++k) {
        const uint2 rr = rp[k];
        const float w = dec_w(rr, t);
        const ushort4 v = *(const ushort4*)(yb + (size_t)(rr.x & 0xFFFFu) * ROW_ELEMS + l4);
        acc.x += bf16_to_f32(v.x) * w;
        acc.y += bf16_to_f32(v.y) * w;
        acc.z += bf16_to_f32(v.z) * w;
        acc.w += bf16_to_f32(v.w) * w;
    }

    const float4 bv = *(const float4*)(b + (lane & 15) * 4);
    acc.x += bv.x; acc.y += bv.y; acc.z += bv.z; acc.w += bv.w;
    *(float4*)(out + (size_t)n * ROW_ELEMS + l4) = acc;
}

extern "C" void kernel_launch(void* const* d_in, const int* in_sizes, int n_in,
                              void* d_out, int out_size, void* d_ws, size_t ws_size,
                              hipStream_t stream) {
    const float* x   = (const float*)d_in[0];  // (N,T,64)
    const float* ew  = (const float*)d_in[1];  // (T,E)
    const int*   src = (const int*)  d_in[2];  // (E,)
    const int*   dst = (const int*)  d_in[3];  // (E,)
    const float* W   = (const float*)d_in[4];  // (64,64)
    const float* b   = (const float*)d_in[5];  // (64,)
    float*       out = (float*)d_out;          // (N,T,64)

    char* ws = (char*)d_ws;
    size_t off = 0;
    auto alloc = [&](size_t bytes) {
        void* p = ws + off;
        off += (bytes + 255) & ~(size_t)255;
        return p;
    };
    unsigned short* yb     = (unsigned short*)alloc((size_t)ROWS * 64 * 2);          // 10.24 MB
    unsigned short* cntmat = (unsigned short*)alloc((size_t)CH * N_NODES * 2);       // 5.12 MB
    unsigned short* base   = (unsigned short*)alloc((size_t)CH * N_NODES * 2);       // 5.12 MB
    int*            local  = (int*)           alloc((size_t)N_NODES * sizeof(int));  // 80 KB
    unsigned short* deg    = (unsigned short*)alloc((size_t)N_NODES * 2);            // 40 KB
    int*            blocksum = (int*)         alloc(NB2 * sizeof(int));
    int*            blockoff = (int*)         alloc(NB2 * sizeof(int));
    uint2*          rec    = (uint2*)         alloc((size_t)E_EDGES * sizeof(uint2)); // 5.12 MB
    (void)ws_size;

    hist_kernel<<<CH, 256, 0, stream>>>(dst, cntmat);
    scan_a_kernel<<<NB2, 256, 0, stream>>>(cntmat, base, local, deg, blocksum);
    scan_b_kernel<<<1, 64, 0, stream>>>(blocksum, blockoff);
    scatter_transform_kernel<<<CH + TRANSFORM_BLOCKS, 256, 0, stream>>>(
        x, W, yb, src, dst, ew, base, local, blockoff, rec);
    accumulate_kernel<<<N_NODES / 4, 256, 0, stream>>>(
        yb, rec, local, deg, blockoff, b, out);
}